// Round 1
// baseline (682.392 us; speedup 1.0000x reference)
//
#include <hip/hip_runtime.h>
#include <cstdint>
#include <cstddef>

typedef unsigned int   u32;
typedef unsigned short u16;

__device__ __forceinline__ float bf2f(u32 bits16) { return __uint_as_float(bits16 << 16); }
__device__ __forceinline__ u16 f2bf(float f) {
  u32 u = __float_as_uint(f);
  u = u + 0x7FFFu + ((u >> 16) & 1u);   // round-to-nearest-even
  return (u16)(u >> 16);
}
__device__ __forceinline__ u32 pk(float a, float b) {
  return (u32)f2bf(a) | ((u32)f2bf(b) << 16);
}
__device__ __forceinline__ float lo16(u32 w) { return bf2f(w & 0xFFFFu); }
__device__ __forceinline__ float hi16(u32 w) { return bf2f(w >> 16); }
__device__ __forceinline__ float frcp(float x) { return __builtin_amdgcn_rcpf(x); }

__device__ __forceinline__ int load_idx(const int* eidx, int is64, long long pos) {
  if (is64) return (int)(((const long long*)eidx)[pos]);
  return eidx[pos];
}

// ---- prep stage 1 (grid 48): parallel weight transforms + edge-index width detect ----
// b 0..31 : WcTmp rows 2b,2b+1  (Wc = Wvl_left @ Wvv; cols 0..63 = Wc_i, 64..127 = Wc_j)
// b 32    : int64-vs-int32 detection -> flag
// b 33    : bc = Wvl_left @ bvv + bvl
// b 34..41: WT_sc slices   b 42..45: WT_v slices jt=0,1 (Wvs halves), stride-256 layout
__global__ void k_prep1(const float* Wss, const float* Wvs,
                        const float* Wsv, const float* Wvv, const float* Wvl,
                        const float* bvv, const float* bvl,
                        const int* eidx, int E, int* flag,
                        float* WT_sc, float* WT_v, float* WcTmp, float* bc) {
  int b = blockIdx.x, tid = threadIdx.x;
  if (b < 32) {
    int c = 2 * b + (tid >> 7), kk = tid & 127;
    float s = 0.f;
    for (int m = 0; m < 64; ++m) s += Wvl[c * 128 + m] * Wvv[m * 128 + kk];
    WcTmp[c * 128 + kk] = s;
  } else if (b == 32) {
    __shared__ int zc;
    if (tid == 0) zc = 0;
    __syncthreads();
    int n = (E < 1024) ? E : 1024;
    int local = 0;
    for (int i = tid; i < n; i += 256) {
      if (eidx[2 * i + 1] == 0) local++;   // high words if int64 (all 0)
    }
    atomicAdd(&zc, local);
    __syncthreads();
    if (tid == 0) *flag = (zc >= (n >> 1)) ? 1 : 0;
  } else if (b == 33) {
    if (tid < 64) {
      float s = 0.f;
      for (int m = 0; m < 64; ++m) s += Wvl[tid * 128 + m] * bvv[m];
      bc[tid] = s + bvl[tid];
    }
  } else if (b < 42) {
    int base = (b - 34) * 2048;
    for (int i = 0; i < 8; ++i) {
      int o = base + i * 256 + tid;
      int k = o >> 8, j = o & 255;
      float v;
      if (j < 64)       v = Wss[j * 128 + k];
      else if (j < 128) v = Wss[(j - 64) * 128 + 64 + k];
      else if (j < 192) v = Wsv[(j - 128) * 128 + k];
      else              v = Wsv[(j - 192) * 128 + 64 + k];
      WT_sc[o] = v;
    }
  } else if (b < 46) {
    int base = (b - 42) * 2048;
    for (int i = 0; i < 8; ++i) {
      int o = base + i * 256 + tid;
      int k = o >> 7, j = o & 127;
      float v = (j < 64) ? Wvs[j * 128 + k] : Wvs[(j - 64) * 128 + 64 + k];
      WT_v[k * 256 + j] = v;   // slices jt=0 (b_i) and jt=1 (b_j)
    }
  }
}

// ---- prep stage 2 (grid 7): bf16 epilogue tables + WT_v slices jt=2,3 (need WcTmp) ----
// Wsl2[(g*64+c)*2+h] = pack(Wsl[c][4g+2h], Wsl[c][4g+2h+1]), g<32
// Wpk : 2048 u32 : Wvl_right packed, same (g,c,h) layout, g<16
// WT_v slices 2,3: WT_v[k*256 + 128 + j] = Wc_i^T (j<64) / Wc_j^T (j>=64)
__global__ void k_prep2(const float* Wsl, const float* Wvl, const float* WcTmp,
                        u32* Wsl2, u32* Wpk, float* WT_v) {
  int b = blockIdx.x, tid = threadIdx.x;
  if (b < 2) {
    for (int i = 0; i < 8; ++i) {
      int o = b * 2048 + i * 256 + tid;
      int h = o & 1, c = (o >> 1) & 63, g = o >> 7;
      int k = 4 * g + 2 * h;
      Wsl2[o] = pk(Wsl[c * 128 + k], Wsl[c * 128 + k + 1]);
    }
  } else if (b == 2) {
    for (int i = 0; i < 8; ++i) {
      int o = i * 256 + tid;
      int h = o & 1, c = (o >> 1) & 63, g = o >> 7;
      int k = 4 * g + 2 * h;
      Wpk[o] = pk(Wvl[c * 128 + 64 + k], Wvl[c * 128 + 64 + k + 1]);
    }
  } else {
    for (int i = 0; i < 8; ++i) {
      int idx = (b - 3) * 2048 + i * 256 + tid;
      int k = idx >> 7, j = idx & 127;
      float v = (j < 64) ? WcTmp[j * 128 + k] : WcTmp[(j - 64) * 128 + 64 + k];
      WT_v[k * 256 + 128 + j] = v;
    }
  }
}

__global__ void k_deg(const int* eidx, const int* flag, const float* attr,
                      float* deg, int* cnt, int E) {
  int e = blockIdx.x * 256 + threadIdx.x;
  if (e >= E) return;
  int is64 = *flag;
  int col = load_idx(eidx, is64, (long long)E + e);
  atomicAdd(&deg[col], attr[e]);
  atomicAdd(&cnt[col], 1);
}

// ---- multi-block exclusive scan of cnt -> rowptr, cursor ----
__global__ void k_scan_red(const int* cnt, int* blocksum, int N) {
  __shared__ int lds[256];
  int tid = threadIdx.x, idx = blockIdx.x * 256 + tid;
  lds[tid] = (idx < N) ? cnt[idx] : 0;
  __syncthreads();
  for (int off = 128; off > 0; off >>= 1) {
    if (tid < off) lds[tid] += lds[tid + off];
    __syncthreads();
  }
  if (tid == 0) blocksum[blockIdx.x] = lds[0];
}

__global__ void k_scan_mid(const int* blocksum, int* blockoff, int NB, int* rowptr, int N, int E) {
  __shared__ int lds[1024];
  int tid = threadIdx.x;
  int v = (tid < NB) ? blocksum[tid] : 0;
  lds[tid] = v;
  __syncthreads();
  for (int off = 1; off < 1024; off <<= 1) {
    int t = (tid >= off) ? lds[tid - off] : 0;
    __syncthreads();
    lds[tid] += t;
    __syncthreads();
  }
  if (tid < NB) blockoff[tid] = lds[tid] - v;   // exclusive
  if (tid == 0) rowptr[N] = E;
}

__global__ void k_scan_out(const int* cnt, const int* blockoff, int* rowptr, int* cursor, int N) {
  __shared__ int lds[256];
  int tid = threadIdx.x, idx = blockIdx.x * 256 + tid;
  int v = (idx < N) ? cnt[idx] : 0;
  lds[tid] = v;
  __syncthreads();
  for (int off = 1; off < 256; off <<= 1) {
    int t = (tid >= off) ? lds[tid - off] : 0;
    __syncthreads();
    lds[tid] += t;
    __syncthreads();
  }
  if (idx < N) {
    int o = blockoff[blockIdx.x] + lds[tid] - v;
    rowptr[idx] = o;
    cursor[idx] = o;
  }
}

// CSR fill: erecA[p]={norm, dx, dy, dz} (d = pos_i - pos_j), erecI[p]=row
__global__ void k_fill(const int* eidx, const int* flag, const float* attr, const float* deg,
                       const float* pos, int* cursor, float4* erecA, int* erecI, int E) {
  int e = blockIdx.x * 256 + threadIdx.x;
  if (e >= E) return;
  int is64 = *flag;
  int r  = load_idx(eidx, is64, e);
  int cl = load_idx(eidx, is64, (long long)E + e);
  float dr = deg[r], dc = deg[cl];
  float disr = (dr > 0.f) ? rsqrtf(dr) : 0.f;
  float disc = (dc > 0.f) ? rsqrtf(dc) : 0.f;
  float nrm = disr * disc * attr[e];
  float dx = pos[cl * 3 + 0] - pos[r * 3 + 0];
  float dy = pos[cl * 3 + 1] - pos[r * 3 + 1];
  float dz = pos[cl * 3 + 2] - pos[r * 3 + 2];
  int p = atomicAdd(&cursor[cl], 1);
  erecA[p] = make_float4(nrm, dx, dy, dz);
  erecI[p] = r;
}

// node GEMM: [N,64] @ WT[64,256] -> bf16 records, packed u32 (a,c) stores.
// rec_i[n]: 512 u16, granule c*8: {a_i, c_i, b_i0, b_i1, b_i2, P0, P1, P2}
// rec_j[n]: 512 u16, granule c*8: {a_j, c_j, b_j0, b_j1, b_j2, R0, R1, R2}
__global__ void k_gemm_sc(const float* X, const float* WT, u32* rec_iw, u32* rec_jw, int N) {
  __shared__ float Xs[64 * 68];
  __shared__ float Ws[64 * 68];
  int tid = threadIdx.x;
  int nb = blockIdx.x * 64;
  for (int i = 0; i < 16; ++i) {
    int flat = tid + i * 256;
    int r = flat >> 6, k = flat & 63;
    Xs[k * 68 + r] = (nb + r < N) ? X[(size_t)(nb + r) * 64 + k] : 0.f;
  }
  int ty = tid >> 4, tx = tid & 15;
  int r0 = ty * 4, c0 = tx * 4;
  float accA[4][4];
  const int order[4] = {0, 2, 1, 3};   // a_i, c_i, a_j, c_j
  for (int t = 0; t < 4; ++t) {
    int jt = order[t];
    __syncthreads();
    for (int i = 0; i < 16; ++i) {
      int flat = tid + i * 256;
      int k = flat >> 6, c = flat & 63;
      Ws[k * 68 + c] = WT[k * 256 + jt * 64 + c];
    }
    __syncthreads();
    float acc[4][4] = {};
    for (int k = 0; k < 64; ++k) {
      float4 a = *(const float4*)&Xs[k * 68 + r0];
      float4 b = *(const float4*)&Ws[k * 68 + c0];
      acc[0][0] += a.x * b.x; acc[0][1] += a.x * b.y; acc[0][2] += a.x * b.z; acc[0][3] += a.x * b.w;
      acc[1][0] += a.y * b.x; acc[1][1] += a.y * b.y; acc[1][2] += a.y * b.z; acc[1][3] += a.y * b.w;
      acc[2][0] += a.z * b.x; acc[2][1] += a.z * b.y; acc[2][2] += a.z * b.z; acc[2][3] += a.z * b.w;
      acc[3][0] += a.w * b.x; acc[3][1] += a.w * b.y; acc[3][2] += a.w * b.z; acc[3][3] += a.w * b.w;
    }
    if (t == 0 || t == 2) {
      for (int ii = 0; ii < 4; ++ii)
        for (int jj = 0; jj < 4; ++jj) accA[ii][jj] = acc[ii][jj];
    } else {
      u32* dst = (t == 1) ? rec_iw : rec_jw;
      for (int ii = 0; ii < 4; ++ii) {
        int n = nb + r0 + ii;
        if (n >= N) continue;
        for (int jj = 0; jj < 4; ++jj) {
          int cc = c0 + jj;
          dst[(size_t)n * 256 + cc * 4] = pk(accA[ii][jj], acc[ii][jj]);
        }
      }
    }
  }
}

// vector GEMM: [3N,64] @ WT[64,256] -> 4 slices:
// jt0: Wvs_left  @ v -> rec_i slots 2..4   jt1: Wvs_right @ v -> rec_j slots 2..4
// jt2: Wc_i      @ v -> rec_i slots 5..7   jt3: Wc_j      @ v -> rec_j slots 5..7
__global__ void k_gemm_v(const float* X, const float* WT, u16* rec_i, u16* rec_j, int M) {
  __shared__ float Xs[64 * 68];
  __shared__ float Ws[64 * 68];
  int tid = threadIdx.x;
  int mb = blockIdx.x * 64;
  for (int i = 0; i < 16; ++i) {
    int flat = tid + i * 256;
    int r = flat >> 6, k = flat & 63;
    Xs[k * 68 + r] = (mb + r < M) ? X[(size_t)(mb + r) * 64 + k] : 0.f;
  }
  int ty = tid >> 4, tx = tid & 15;
  int r0 = ty * 4, c0 = tx * 4;
  for (int jt = 0; jt < 4; ++jt) {
    __syncthreads();
    for (int i = 0; i < 16; ++i) {
      int flat = tid + i * 256;
      int k = flat >> 6, c = flat & 63;
      Ws[k * 68 + c] = WT[k * 256 + jt * 64 + c];
    }
    __syncthreads();
    float acc[4][4] = {};
    for (int k = 0; k < 64; ++k) {
      float4 a = *(const float4*)&Xs[k * 68 + r0];
      float4 b = *(const float4*)&Ws[k * 68 + c0];
      acc[0][0] += a.x * b.x; acc[0][1] += a.x * b.y; acc[0][2] += a.x * b.z; acc[0][3] += a.x * b.w;
      acc[1][0] += a.y * b.x; acc[1][1] += a.y * b.y; acc[1][2] += a.y * b.z; acc[1][3] += a.y * b.w;
      acc[2][0] += a.z * b.x; acc[2][1] += a.z * b.y; acc[2][2] += a.z * b.z; acc[2][3] += a.z * b.w;
      acc[3][0] += a.w * b.x; acc[3][1] += a.w * b.y; acc[3][2] += a.w * b.z; acc[3][3] += a.w * b.w;
    }
    u16* dst = (jt & 1) ? rec_j : rec_i;
    int slot = (jt < 2) ? 2 : 5;
    for (int ii = 0; ii < 4; ++ii) {
      int m = mb + r0 + ii;
      if (m >= M) continue;
      int n = m / 3, d = m - n * 3;
      for (int jj = 0; jj < 4; ++jj) {
        int cc = c0 + jj;
        dst[(size_t)n * 512 + cc * 8 + slot + d] = f2bf(acc[ii][jj]);
      }
    }
  }
}

// Fused hot kernel: one wave per node, wave-uniform scalar edge metadata,
// 2-edge unrolled loop with double prefetch, in-wave epilogue matvecs.
// Vector head restructured: x-part (wa*Wc_i@v_i) precomputed as P_i in rec_i,
// y-part (Wc_j@v_j) precomputed as R_j in rec_j (accumulated by the edge loop
// g-accumulators) -> only the nonlinear t-part remains as a 64-wide matvec.
__global__ __launch_bounds__(512) void k_edges(
    const u16* __restrict__ rec_i, const u16* __restrict__ rec_j,
    const float4* __restrict__ erecA, const int* __restrict__ erecI,
    const int* __restrict__ rowptr,
    const float* __restrict__ scalar, const float* __restrict__ vector,
    const float* __restrict__ bss, const float* __restrict__ bvs,
    const float* __restrict__ bsv, const float* __restrict__ bsl,
    const u32* __restrict__ Wsl2g, const u32* __restrict__ Wpkg,
    const float* __restrict__ bcg,
    float* __restrict__ out_s, float* __restrict__ out_v, int N) {
  __shared__ u32 sWsl[4096];        // 16 KB
  __shared__ u32 sWv[2048];         // 8 KB  (Wvl_right only)
  __shared__ float sStage[8 * 128]; // 4 KB, wave-private epilogue stage
  int tid = threadIdx.x, lane = tid & 63, wv = tid >> 6;
  for (int o = tid; o < 4096; o += 512) sWsl[o] = Wsl2g[o];
  for (int o = tid; o < 2048; o += 512) sWv[o] = Wpkg[o];
  __syncthreads();   // the only block barrier

  int node = __builtin_amdgcn_readfirstlane((int)(blockIdx.x * 8) + wv);
  if (node >= N) node = N - 1;

  uint4 riv = *(const uint4*)(rec_i + ((size_t)node << 9) + lane * 8);
  float aiB  = lo16(riv.x) + bss[lane];
  float ciB  = hi16(riv.x) + bsv[lane];
  float Bvs  = bvs[lane];
  float bib0 = lo16(riv.y) + Bvs;
  float bib1 = hi16(riv.y) + Bvs;
  float bib2 = lo16(riv.z) + Bvs;
  float Pi0  = hi16(riv.z), Pi1 = lo16(riv.w), Pi2 = hi16(riv.w);
  float bsl_c = bsl[lane], bc_c = bcg[lane];

  float us = 0, uv = 0, t0 = 0, t1 = 0, t2 = 0, g0 = 0, g1 = 0, g2 = 0, wa = 0;
  int rp = rowptr[node], re = rowptr[node + 1];
  u32 lim = (u32)(N - 1);
  u32 lane16 = (u32)lane << 4;
  const char* rjb = (const char*)rec_j;

  // erecI has 64 ints of slack past E; poison values clamp via min()
  u32 ra = min((u32)erecI[rp], lim);
  u32 rb = min((u32)erecI[rp + 1], lim);
  uint4 pre0 = *(const uint4*)(rjb + ((ra << 10) + lane16));
  uint4 pre1 = *(const uint4*)(rjb + ((rb << 10) + lane16));
  int p = rp;
  #define EDGE_MATH(CUR, EV)                                                  \
    {                                                                         \
      float nrm = EV.x, dx = EV.y, dy = EV.z, dz = EV.w;                      \
      float aj  = lo16(CUR.x), cj  = hi16(CUR.x);                             \
      float bj0 = lo16(CUR.y), bj1 = hi16(CUR.y), bj2 = lo16(CUR.z);          \
      float rj0 = hi16(CUR.z), rj1 = lo16(CUR.w), rj2 = hi16(CUR.w);          \
      float xs  = aiB + aj;                                                   \
      float s2s = xs * frcp(1.f + __expf(-xs));                               \
      float y   = (bib0 + bj0) * dx;                                          \
      y = fmaf(bib1 + bj1, dy, y);                                            \
      y = fmaf(bib2 + bj2, dz, y);                                            \
      float v2s = y * frcp(1.f + __expf(-y));                                 \
      float qh  = 2.8853900817779268f * (ciB + cj);                           \
      float th0 = fmaf(-2.f, frcp(1.f + exp2f(qh * dx)), 1.f);                \
      float th1 = fmaf(-2.f, frcp(1.f + exp2f(qh * dy)), 1.f);                \
      float th2 = fmaf(-2.f, frcp(1.f + exp2f(qh * dz)), 1.f);                \
      us = fmaf(nrm, s2s, us); uv = fmaf(nrm, v2s, uv);                       \
      t0 = fmaf(nrm, th0, t0); t1 = fmaf(nrm, th1, t1); t2 = fmaf(nrm, th2, t2);\
      g0 = fmaf(nrm, rj0, g0); g1 = fmaf(nrm, rj1, g1); g2 = fmaf(nrm, rj2, g2);\
      wa += nrm;                                                              \
    }
  for (; p + 1 < re; p += 2) {
    uint4 cur0 = pre0, cur1 = pre1;
    u32 rn0 = min((u32)erecI[p + 2], lim);
    u32 rn1 = min((u32)erecI[p + 3], lim);
    pre0 = *(const uint4*)(rjb + ((rn0 << 10) + lane16));
    pre1 = *(const uint4*)(rjb + ((rn1 << 10) + lane16));
    float4 e0 = erecA[p];
    float4 e1 = erecA[p + 1];
    EDGE_MATH(cur0, e0)
    EDGE_MATH(cur1, e1)
  }
  if (p < re) {
    uint4 cur0 = pre0;
    float4 e0 = erecA[p];
    EDGE_MATH(cur0, e0)
  }
  #undef EDGE_MATH

  // ---- epilogue: scalar head (wave-local, no block barrier) ----
  float* mys = &sStage[wv * 128];
  mys[lane] = us; mys[64 + lane] = uv;
  __threadfence_block();
  float acc = wa * bsl_c;
  #pragma unroll
  for (int g = 0; g < 32; ++g) {
    float4 u = *(const float4*)&mys[4 * g];
    uint2 w = *(const uint2*)&sWsl[(g * 64 + lane) * 2];
    acc = fmaf(u.x, lo16(w.x), acc);
    acc = fmaf(u.y, hi16(w.x), acc);
    acc = fmaf(u.z, lo16(w.y), acc);
    acc = fmaf(u.w, hi16(w.y), acc);
  }
  size_t so = ((size_t)node << 6) + lane;
  out_s[so] = acc * frcp(1.f + __expf(-acc)) + scalar[so];

  // ---- epilogue: vector head (t-part matvec only; x,y parts precomputed) ----
  float gg[3] = {g0, g1, g2}, tt[3] = {t0, t1, t2}, Pi[3] = {Pi0, Pi1, Pi2};
  #pragma unroll
  for (int d = 0; d < 3; ++d) {
    size_t vo = (((size_t)node * 3 + d) << 6) + lane;
    float vid = vector[vo];
    __threadfence_block();
    mys[lane] = tt[d];
    __threadfence_block();
    float a2 = fmaf(wa, bc_c + Pi[d], gg[d]);
    #pragma unroll
    for (int g = 0; g < 16; ++g) {
      float4 tu = *(const float4*)&mys[4 * g];
      uint2 w = *(const uint2*)&sWv[(g * 64 + lane) * 2];
      a2 = fmaf(tu.x, lo16(w.x), a2); a2 = fmaf(tu.y, hi16(w.x), a2);
      a2 = fmaf(tu.z, lo16(w.y), a2); a2 = fmaf(tu.w, hi16(w.y), a2);
    }
    float th = fmaf(-2.f, frcp(1.f + exp2f(2.8853900817779268f * a2)), 1.f);
    out_v[vo] = th + vid;
  }
}

extern "C" void kernel_launch(void* const* d_in, const int* in_sizes, int n_in,
                              void* d_out, int out_size, void* d_ws, size_t ws_size,
                              hipStream_t stream) {
  const float* scalar   = (const float*)d_in[0];
  const float* vector   = (const float*)d_in[1];
  const float* position = (const float*)d_in[2];
  const int*   eidx     = (const int*)d_in[3];
  const float* attr     = (const float*)d_in[4];
  const float* Wss = (const float*)d_in[5];
  const float* bss = (const float*)d_in[6];
  const float* Wvs = (const float*)d_in[7];
  const float* bvs = (const float*)d_in[8];
  const float* Wsl = (const float*)d_in[9];
  const float* bsl = (const float*)d_in[10];
  const float* Wsv = (const float*)d_in[11];
  const float* bsv = (const float*)d_in[12];
  const float* Wvv = (const float*)d_in[13];
  const float* bvv = (const float*)d_in[14];
  const float* Wvl = (const float*)d_in[15];
  const float* bvl = (const float*)d_in[16];

  int N = in_sizes[0] / 64;
  int E = in_sizes[4];
  int M = 3 * N;
  int NB = (N + 255) / 256;   // scan blocks (must be <= 1024)

  char* wsb = (char*)d_ws;
  size_t off = 0;
  auto alloc = [&](size_t bytes) -> char* {
    char* p = wsb + off;
    off += (bytes + 255) & ~(size_t)255;
    return p;
  };
  float*  deg    = (float*)alloc((size_t)N * 4);
  int*    cnt    = (int*)alloc((size_t)N * 4);
  int*    rowptr = (int*)alloc((size_t)(N + 1) * 4);
  int*    cursor = (int*)alloc((size_t)N * 4);
  int*    blocksum = (int*)alloc((size_t)NB * 4);
  int*    blockoff = (int*)alloc((size_t)NB * 4);
  float4* erecA  = (float4*)alloc((size_t)E * 16);
  int*    erecI  = (int*)alloc((size_t)(E + 64) * 4);   // +slack for prefetch reads
  u16*    rec_i  = (u16*)alloc((size_t)N * 512 * 2);
  u16*    rec_j  = (u16*)alloc((size_t)N * 512 * 2);
  float*  WT_sc  = (float*)alloc(64 * 256 * 4);
  float*  WT_v   = (float*)alloc(64 * 256 * 4);
  u32*    Wsl2   = (u32*)alloc(4096 * 4);
  u32*    Wpk    = (u32*)alloc(2048 * 4);
  float*  WcTmp  = (float*)alloc(64 * 128 * 4);
  float*  bc     = (float*)alloc(64 * 4);
  int*    flag   = (int*)alloc(4);
  (void)ws_size; (void)n_in; (void)out_size;

  // zero deg + cnt (contiguous region)
  hipMemsetAsync(deg, 0, (size_t)((char*)rowptr - (char*)deg), stream);

  k_prep1<<<48, 256, 0, stream>>>(Wss, Wvs, Wsv, Wvv, Wvl, bvv, bvl,
                                  eidx, E, flag, WT_sc, WT_v, WcTmp, bc);
  k_prep2<<<7, 256, 0, stream>>>(Wsl, Wvl, WcTmp, Wsl2, Wpk, WT_v);
  k_deg<<<(E + 255) / 256, 256, 0, stream>>>(eidx, flag, attr, deg, cnt, E);
  k_scan_red<<<NB, 256, 0, stream>>>(cnt, blocksum, N);
  k_scan_mid<<<1, 1024, 0, stream>>>(blocksum, blockoff, NB, rowptr, N, E);
  k_scan_out<<<NB, 256, 0, stream>>>(cnt, blockoff, rowptr, cursor, N);
  k_fill<<<(E + 255) / 256, 256, 0, stream>>>(eidx, flag, attr, deg, position, cursor, erecA, erecI, E);
  k_gemm_sc<<<(N + 63) / 64, 256, 0, stream>>>(scalar, WT_sc, (u32*)rec_i, (u32*)rec_j, N);
  k_gemm_v<<<(M + 63) / 64, 256, 0, stream>>>(vector, WT_v, rec_i, rec_j, M);
  k_edges<<<(N + 7) / 8, 512, 0, stream>>>(rec_i, rec_j, erecA, erecI, rowptr,
                                           scalar, vector, bss, bvs, bsv, bsl,
                                           Wsl2, Wpk, bc,
                                           (float*)d_out, (float*)d_out + (size_t)N * 64, N);
}